// Round 8
// baseline (664.843 us; speedup 1.0000x reference)
//
#include <hip/hip_runtime.h>
#include <hip/hip_bf16.h>

#define DIM 128
#define HIDDEN 384
#define BATCH 4
#define NDATA 100000
#define NEDGE 200000
#define NLOG 4096

typedef __bf16 bf16x8 __attribute__((ext_vector_type(8)));
typedef __bf16 bf16x2 __attribute__((ext_vector_type(2)));
typedef float f32x4 __attribute__((ext_vector_type(4)));
typedef unsigned short u16;
typedef unsigned int u32;

__device__ __forceinline__ u16 f2bf(float f) {
  __bf16 b = (__bf16)f;  // native RNE convert (v_cvt_pk_bf16_f32)
  return __builtin_bit_cast(u16, b);
}
// packed pair convert: single v_cvt_pk_bf16_f32
__device__ __forceinline__ u32 pk2bf(float lo, float hi) {
  bf16x2 t;
  t[0] = (__bf16)lo;
  t[1] = (__bf16)hi;
  return __builtin_bit_cast(u32, t);
}
__device__ __forceinline__ bf16x8 as_bf(uint4 u) {
  return __builtin_bit_cast(bf16x8, u);
}
// tanh via e^{2x}; v_rcp_f32 (1 ulp) -- abs err ~1e-7, << bf16 path error
__device__ __forceinline__ float fast_tanh(float x) {
  float xc = fminf(fmaxf(x, -15.f), 15.f);
  float t = __expf(2.f * xc);
  return (t - 1.f) * __builtin_amdgcn_rcpf(t + 1.f);
}

// ---------------------------------------------------------------------------
// CSR build: histogram -> scan -> scatter
// ---------------------------------------------------------------------------
__global__ void zero_counts_kernel(int* __restrict__ counts) {
  int i = blockIdx.x * blockDim.x + threadIdx.x;
  if (i < NLOG) counts[i] = 0;
}

__global__ void count_kernel(const int* __restrict__ dst, int* __restrict__ counts) {
  int e = blockIdx.x * blockDim.x + threadIdx.x;
  if (e < NEDGE) atomicAdd(&counts[dst[e]], 1);
}

__global__ __launch_bounds__(1024) void scan_kernel(const int* __restrict__ counts,
                                                    int* __restrict__ offsets,
                                                    int* __restrict__ cursor) {
  __shared__ int sdata[1024];
  const int t = threadIdx.x;
  const int c0 = counts[4 * t + 0];
  const int c1 = counts[4 * t + 1];
  const int c2 = counts[4 * t + 2];
  const int c3 = counts[4 * t + 3];
  const int s = c0 + c1 + c2 + c3;
  sdata[t] = s;
  __syncthreads();
  for (int off = 1; off < 1024; off <<= 1) {
    int vv = (t >= off) ? sdata[t - off] : 0;
    __syncthreads();
    sdata[t] += vv;
    __syncthreads();
  }
  const int excl = sdata[t] - s;
  const int o0 = excl, o1 = o0 + c0, o2 = o1 + c1, o3 = o2 + c2;
  offsets[4 * t + 0] = o0;
  offsets[4 * t + 1] = o1;
  offsets[4 * t + 2] = o2;
  offsets[4 * t + 3] = o3;
  cursor[4 * t + 0] = o0;
  cursor[4 * t + 1] = o1;
  cursor[4 * t + 2] = o2;
  cursor[4 * t + 3] = o3;
  if (t == 1023) offsets[NLOG] = o3 + c3;
}

__global__ void scatter_kernel(const int* __restrict__ src, const int* __restrict__ dst,
                               int* __restrict__ cursor, int* __restrict__ sorted_src) {
  int e = blockIdx.x * blockDim.x + threadIdx.x;
  if (e < NEDGE) {
    int d = dst[e];
    int pos = atomicAdd(&cursor[d], 1);
    sorted_src[pos] = src[e];
  }
}

// ---------------------------------------------------------------------------
// segment product over bf16 v_act [i][b][dim]: one block (4 WAVES) per
// segment. Wave w handles the w-th quarter of the edge list (chunked) ->
// 4x shorter serial load chains + 32 waves/CU resident; partial products
// combined through LDS (multiplication exact-commutative).
// Each thread covers 8 bf16 = 16 B; 64 lanes = exactly one 1 KB row.
// ---------------------------------------------------------------------------
__device__ __forceinline__ void prod_accum(uint4 u, f32x4& plo, f32x4& phi) {
  f32x4 lo, hi;
  lo[0] = __uint_as_float(u.x << 16);
  lo[1] = __uint_as_float(u.x & 0xffff0000u);
  lo[2] = __uint_as_float(u.y << 16);
  lo[3] = __uint_as_float(u.y & 0xffff0000u);
  hi[0] = __uint_as_float(u.z << 16);
  hi[1] = __uint_as_float(u.z & 0xffff0000u);
  hi[2] = __uint_as_float(u.w << 16);
  hi[3] = __uint_as_float(u.w & 0xffff0000u);
  plo *= lo;
  phi *= hi;
}

__global__ __launch_bounds__(256) void prod_kernel_t(const u16* __restrict__ va,
                                                     const int* __restrict__ offsets,
                                                     const int* __restrict__ sorted_src,
                                                     float* __restrict__ l) {
  __shared__ f32x4 part[3][64][2];  // waves 1..3 partial products, 6 KB
  const int s = blockIdx.x;
  const int t = threadIdx.x;
  const int w = t >> 6;
  const int c = t & 63;  // covers bf16 elems 8c..8c+7 of the 512-elem row
  const int beg = offsets[s];
  const int end = offsets[s + 1];
  const int len = end - beg;
  const int qb = beg + ((len * w) >> 2);
  const int qe = beg + ((len * (w + 1)) >> 2);
  const u16* base = va + 8 * c;
  f32x4 plo[8], phi[8];
#pragma unroll
  for (int i = 0; i < 8; ++i) {
    plo[i] = {1.f, 1.f, 1.f, 1.f};
    phi[i] = {1.f, 1.f, 1.f, 1.f};
  }
  int e = qb;
  // scalar head until e is int4-aligned
  for (; e < qe && (e & 3); ++e) {
    const uint4 u = *(const uint4*)(base + (size_t)sorted_src[e] * 512);
    prod_accum(u, plo[0], phi[0]);
  }
  for (; e + 8 <= qe; e += 8) {
    const int4 ia = *(const int4*)(sorted_src + e);
    const int4 ib = *(const int4*)(sorted_src + e + 4);
    const int idx[8] = {ia.x, ia.y, ia.z, ia.w, ib.x, ib.y, ib.z, ib.w};
    uint4 r[8];
#pragma unroll
    for (int i = 0; i < 8; ++i) r[i] = *(const uint4*)(base + (size_t)idx[i] * 512);
#pragma unroll
    for (int i = 0; i < 8; ++i) prod_accum(r[i], plo[i], phi[i]);
  }
  for (; e < qe; ++e) {
    const uint4 u = *(const uint4*)(base + (size_t)sorted_src[e] * 512);
    prod_accum(u, plo[0], phi[0]);
  }
  f32x4 rlo =
      ((plo[0] * plo[1]) * (plo[2] * plo[3])) * ((plo[4] * plo[5]) * (plo[6] * plo[7]));
  f32x4 rhi =
      ((phi[0] * phi[1]) * (phi[2] * phi[3])) * ((phi[4] * phi[5]) * (phi[6] * phi[7]));
  if (w) {
    part[w - 1][c][0] = rlo;
    part[w - 1][c][1] = rhi;
  }
  __syncthreads();
  if (w == 0) {
#pragma unroll
    for (int i = 0; i < 3; ++i) {
      rlo *= part[i][c][0];
      rhi *= part[i][c][1];
    }
    // elems 8c..8c+7 -> batch b = c>>4, dim d = (c&15)*8
    float* outp = l + ((size_t)(c >> 4) * NLOG + s) * DIM + (c & 15) * 8;
    *(f32x4*)outp = rlo;
    *(f32x4*)(outp + 4) = rhi;
  }
}

// ---------------------------------------------------------------------------
// weight convert: fp32 -> bf16, transposed to [N][K] (K contiguous)
// ---------------------------------------------------------------------------
__global__ __launch_bounds__(256) void convert_w_kernel(
    const float* __restrict__ w1a, const float* __restrict__ w3a,
    const float* __restrict__ w2a, const float* __restrict__ w1b,
    const float* __restrict__ w3b, const float* __restrict__ w2b,
    u16* __restrict__ w1Ta, u16* __restrict__ w3Ta, u16* __restrict__ w2Ta,
    u16* __restrict__ w1Tb, u16* __restrict__ w3Tb, u16* __restrict__ w2Tb) {
  const int i = blockIdx.x * 256 + threadIdx.x;  // 0..49151 exact
  const int n1 = i >> 7, k1 = i & 127;           // w1T/w3T: [384][128]
  w1Ta[i] = f2bf(w1a[k1 * HIDDEN + n1]);
  w3Ta[i] = f2bf(w3a[k1 * HIDDEN + n1]);
  w1Tb[i] = f2bf(w1b[k1 * HIDDEN + n1]);
  w3Tb[i] = f2bf(w3b[k1 * HIDDEN + n1]);
  const int n2 = i / HIDDEN, k2 = i - n2 * HIDDEN;  // w2T: [128][384]
  w2Ta[i] = f2bf(w2a[k2 * DIM + n2]);
  w2Tb[i] = f2bf(w2b[k2 * DIM + n2]);
}

// ---------------------------------------------------------------------------
// Fused MFMA FFN, transposed GEMMs: D = W^T (A, global) x X^T (B, LDS).
// R1 base structure (64-row tile, 48 KB LDS, 3 blocks/CU) + ROTATED
// pipeline: per mt, MFMA(mt) -> issue mt+1 weight loads into the SAME
// a1/a3 regs (WAR resolves at MFMA issue; no snapshot arrays, no extra
// regs -- R4's spill trap avoided) -> epilogue VALU (~300+ cyc) covers
// the L2 latency. GEMM2: residual loads hoisted above nt loop.
// LDS: xn[64][128]bf16 in [0,16K) until B-frags hoisted; gs[64][384] reuses.
// Swizzle: physical 16B chunk = logical ^ (row&7) on both write & read.
// mode: 1 = ffn1 (tanh + transposed BF16 store [i][b][dim]), 0 = ffn2 (f32).
// ---------------------------------------------------------------------------
__global__ __launch_bounds__(256, 3) void ffn_mfma_kernel(
    const float* __restrict__ xin, const float* __restrict__ rmsw,
    const u16* __restrict__ w1T, const u16* __restrict__ w3T,
    const u16* __restrict__ w2T, float* __restrict__ xout, int mode) {
  __shared__ alignas(16) u16 sm[24576];  // 49152 B
  char* const sb = (char*)sm;
  const int t = threadIdx.x;
  const int row0 = blockIdx.x * 64;

  // ---- Phase A: load + rmsnorm -> xn (bf16, swizzled 16B chunks) ----
  {
    const int r = t >> 2;  // 0..63
    const int q = t & 3;   // 32-col slice
    const float* vr = xin + (size_t)(row0 + r) * DIM + q * 32;
    float av[32];
#pragma unroll
    for (int i = 0; i < 8; ++i) *(float4*)(av + 4 * i) = *(const float4*)(vr + 4 * i);
    float wr_[32];
#pragma unroll
    for (int i = 0; i < 8; ++i)
      *(float4*)(wr_ + 4 * i) = *(const float4*)(rmsw + q * 32 + 4 * i);
    float ss = 0.f;
#pragma unroll
    for (int i = 0; i < 32; ++i) ss += av[i] * av[i];
    ss += __shfl_xor(ss, 1);
    ss += __shfl_xor(ss, 2);
    const float scale = __builtin_amdgcn_rsqf(ss * (1.0f / DIM) + 1e-5f);
    const int r7 = r & 7;
#pragma unroll
    for (int i = 0; i < 4; ++i) {
      uint4 pk;
      pk.x = pk2bf(av[8 * i + 0] * scale * wr_[8 * i + 0],
                   av[8 * i + 1] * scale * wr_[8 * i + 1]);
      pk.y = pk2bf(av[8 * i + 2] * scale * wr_[8 * i + 2],
                   av[8 * i + 3] * scale * wr_[8 * i + 3]);
      pk.z = pk2bf(av[8 * i + 4] * scale * wr_[8 * i + 4],
                   av[8 * i + 5] * scale * wr_[8 * i + 5]);
      pk.w = pk2bf(av[8 * i + 6] * scale * wr_[8 * i + 6],
                   av[8 * i + 7] * scale * wr_[8 * i + 7]);
      const int c = q * 4 + i;
      *(uint4*)(sb + r * 256 + ((c ^ r7) << 4)) = pk;
    }
  }
  __syncthreads();

  const int wv = t >> 6;
  const int lane = t & 63;
  const int m16 = lane & 15;
  const int quad = lane >> 4;
  const int m7 = m16 & 7;

  // ---- B-fragments (xn) hoisted once: all 64 rows x K=128 ----
  uint4 bfr[4][4];
#pragma unroll
  for (int nt = 0; nt < 4; ++nt) {
    const int row = nt * 16 + m16;
#pragma unroll
    for (int ks = 0; ks < 4; ++ks)
      bfr[nt][ks] = *(const uint4*)(sb + row * 256 + (((4 * ks + quad) ^ m7) << 4));
  }
  __syncthreads();  // xn region is now dead; gs may alias it

  // ---- GEMM1 (rotated pipeline): gs = silu(h1)*h3 -> LDS ----
  const int woff = wv * 96;  // this wave's hidden slice
  uint4 a1[4], a3[4];
  {
    const size_t wrow0 = (size_t)(woff + m16) * DIM + quad * 8;
#pragma unroll
    for (int ks = 0; ks < 4; ++ks) {
      a1[ks] = *(const uint4*)(w1T + wrow0 + ks * 32);
      a3[ks] = *(const uint4*)(w3T + wrow0 + ks * 32);
    }
  }
#pragma unroll 1
  for (int mt = 0; mt < 6; ++mt) {
    f32x4 acc1[4] = {{0.f, 0.f, 0.f, 0.f}, {0.f, 0.f, 0.f, 0.f},
                     {0.f, 0.f, 0.f, 0.f}, {0.f, 0.f, 0.f, 0.f}};
    f32x4 acc3[4] = {{0.f, 0.f, 0.f, 0.f}, {0.f, 0.f, 0.f, 0.f},
                     {0.f, 0.f, 0.f, 0.f}, {0.f, 0.f, 0.f, 0.f}};
#pragma unroll
    for (int ks = 0; ks < 4; ++ks) {
      const bf16x8 fa1 = as_bf(a1[ks]);
      const bf16x8 fa3 = as_bf(a3[ks]);
#pragma unroll
      for (int nt = 0; nt < 4; ++nt) {
        const bf16x8 fb = as_bf(bfr[nt][ks]);
        acc1[nt] = __builtin_amdgcn_mfma_f32_16x16x32_bf16(fa1, fb, acc1[nt], 0, 0, 0);
        acc3[nt] = __builtin_amdgcn_mfma_f32_16x16x32_bf16(fa3, fb, acc3[nt], 0, 0, 0);
      }
    }
    // issue mt+1 weight loads into the SAME registers (after last MFMA read);
    // the epilogue below covers their latency
    if (mt < 5) {
      const size_t wrown = (size_t)(woff + (mt + 1) * 16 + m16) * DIM + quad * 8;
#pragma unroll
      for (int ks = 0; ks < 4; ++ks) {
        a1[ks] = *(const uint4*)(w1T + wrown + ks * 32);
        a3[ks] = *(const uint4*)(w3T + wrown + ks * 32);
      }
    }
    // epilogue: lane holds 4 consecutive hidden (h0..h0+3) at 4 rows (nt)
    const int hch = (woff + mt * 16) >> 3;  // even chunk base
    const int chu = (hch + (quad >> 1));
    const int half = (quad & 1) * 8;
#pragma unroll
    for (int nt = 0; nt < 4; ++nt) {
      const int row = nt * 16 + m16;
      float g[4];
#pragma unroll
      for (int r = 0; r < 4; ++r) {
        const float h1 = acc1[nt][r], h3 = acc3[nt][r];
        g[r] = h1 * __builtin_amdgcn_rcpf(1.0f + __expf(-h1)) * h3;
      }
      uint2 pk;
      pk.x = pk2bf(g[0], g[1]);
      pk.y = pk2bf(g[2], g[3]);
      *(uint2*)(sb + row * 768 + ((chu ^ m7) << 4) + half) = pk;
    }
  }
  __syncthreads();

  // ---- GEMM2: F^T = W2^T @ G^T (+residual); residuals hoisted per mt ----
#pragma unroll 1
  for (int mt = 0; mt < 2; ++mt) {
    const size_t wrow = (size_t)(wv * 32 + mt * 16 + m16) * HIDDEN + quad * 8;
    const int d0 = wv * 32 + mt * 16 + quad * 4;
    uint4 aw[12];
#pragma unroll
    for (int ks = 0; ks < 12; ++ks) aw[ks] = *(const uint4*)(w2T + wrow + ks * 32);
    float4 res[4];
#pragma unroll
    for (int nt = 0; nt < 4; ++nt)
      res[nt] = *(const float4*)(xin + (size_t)(row0 + nt * 16 + m16) * DIM + d0);
#pragma unroll 1
    for (int nt = 0; nt < 4; ++nt) {
      const int row = nt * 16 + m16;
      uint4 bg[12];
#pragma unroll
      for (int ks = 0; ks < 12; ++ks)
        bg[ks] = *(const uint4*)(sb + row * 768 + (((4 * ks + quad) ^ m7) << 4));
      f32x4 acc = {0.f, 0.f, 0.f, 0.f};
#pragma unroll
      for (int ks = 0; ks < 12; ++ks)
        acc = __builtin_amdgcn_mfma_f32_16x16x32_bf16(as_bf(aw[ks]), as_bf(bg[ks]), acc,
                                                      0, 0, 0);
      const int grow = row0 + row;
      float4 o;
      o.x = acc[0] + res[nt].x;
      o.y = acc[1] + res[nt].y;
      o.z = acc[2] + res[nt].z;
      o.w = acc[3] + res[nt].w;
      if (mode) {  // ffn1: tanh + transposed BF16 store [i][b][dim]
        o.x = fast_tanh(o.x);
        o.y = fast_tanh(o.y);
        o.z = fast_tanh(o.z);
        o.w = fast_tanh(o.w);
        const int b = grow / NDATA;
        const int i = grow - b * NDATA;
        u16* const xb = (u16*)xout;
        uint2 pk;
        pk.x = pk2bf(o.x, o.y);
        pk.y = pk2bf(o.z, o.w);
        *(uint2*)(xb + ((size_t)i * BATCH + b) * DIM + d0) = pk;
      } else {
        *(float4*)(xout + (size_t)grow * DIM + d0) = o;
      }
    }
  }
}

// ---------------------------------------------------------------------------
// readout: out[row] = dot(fbuf[row], wout) + bout
// ---------------------------------------------------------------------------
__global__ __launch_bounds__(256) void readout_kernel(const float* __restrict__ fbuf,
                                                      const float* __restrict__ wout,
                                                      const float* __restrict__ bout,
                                                      float* __restrict__ out) {
  const int t = threadIdx.x;
  const int row = blockIdx.x * 4 + (t >> 6);
  const int lane = t & 63;
  const float2 f = *(const float2*)(fbuf + (size_t)row * DIM + lane * 2);
  const float2 w = *(const float2*)(wout + lane * 2);
  float s = f.x * w.x + f.y * w.y;
  s += __shfl_xor(s, 1);
  s += __shfl_xor(s, 2);
  s += __shfl_xor(s, 4);
  s += __shfl_xor(s, 8);
  s += __shfl_xor(s, 16);
  s += __shfl_xor(s, 32);
  if (lane == 0) out[row] = s + bout[0];
}

// ---------------------------------------------------------------------------
extern "C" void kernel_launch(void* const* d_in, const int* in_sizes, int n_in,
                              void* d_out, int out_size, void* d_ws, size_t ws_size,
                              hipStream_t stream) {
  const float* v = (const float*)d_in[0];
  const int* data_src = (const int*)d_in[1];
  const int* data_dst = (const int*)d_in[2];
  const float* rms1_w = (const float*)d_in[4];
  const float* w1a = (const float*)d_in[5];
  const float* w2a = (const float*)d_in[6];
  const float* w3a = (const float*)d_in[7];
  const float* rms2_w = (const float*)d_in[8];
  const float* w1b = (const float*)d_in[9];
  const float* w2b = (const float*)d_in[10];
  const float* w3b = (const float*)d_in[11];
  const float* wout = (const float*)d_in[12];
  const float* bout = (const float*)d_in[13];
  float* out = (float*)d_out;

  char* ws = (char*)d_ws;
  size_t off = 0;
  auto take = [&](size_t bytes) -> char* {
    char* p = ws + off;
    off += (bytes + 255) & ~(size_t)255;
    return p;
  };
  u16* v_act_t = (u16*)take((size_t)BATCH * NDATA * DIM * 2);  // [i][b][dim] bf16
  float* lbuf = (float*)take((size_t)BATCH * NLOG * DIM * 4);
  float* fbuf = (float*)take((size_t)BATCH * NLOG * DIM * 4);
  int* counts = (int*)take(NLOG * 4);
  int* offsets = (int*)take((NLOG + 1) * 4);
  int* cursor = (int*)take(NLOG * 4);
  int* sorted_src = (int*)take(NEDGE * 4);
  u16* w1Ta = (u16*)take(HIDDEN * DIM * 2);
  u16* w3Ta = (u16*)take(HIDDEN * DIM * 2);
  u16* w2Ta = (u16*)take(HIDDEN * DIM * 2);
  u16* w1Tb = (u16*)take(HIDDEN * DIM * 2);
  u16* w3Tb = (u16*)take(HIDDEN * DIM * 2);
  u16* w2Tb = (u16*)take(HIDDEN * DIM * 2);

  convert_w_kernel<<<(HIDDEN * DIM) / 256, 256, 0, stream>>>(
      w1a, w3a, w2a, w1b, w3b, w2b, w1Ta, w3Ta, w2Ta, w1Tb, w3Tb, w2Tb);
  zero_counts_kernel<<<(NLOG + 255) / 256, 256, 0, stream>>>(counts);
  count_kernel<<<(NEDGE + 255) / 256, 256, 0, stream>>>(data_dst, counts);
  scan_kernel<<<1, 1024, 0, stream>>>(counts, offsets, cursor);
  scatter_kernel<<<(NEDGE + 255) / 256, 256, 0, stream>>>(data_src, data_dst, cursor,
                                                          sorted_src);
  // FFN1 + tanh over 400k rows -> transposed bf16 v_act
  ffn_mfma_kernel<<<(BATCH * NDATA) / 64, 256, 0, stream>>>(
      v, rms1_w, w1Ta, w3Ta, w2Ta, (float*)v_act_t, 1);
  // segment products: 4 waves per segment, LDS combine
  prod_kernel_t<<<NLOG, 256, 0, stream>>>(v_act_t, offsets, sorted_src, lbuf);
  // FFN2 (flat f32) + readout
  ffn_mfma_kernel<<<(BATCH * NLOG) / 64, 256, 0, stream>>>(lbuf, rms2_w, w1Tb, w3Tb,
                                                           w2Tb, fbuf, 0);
  readout_kernel<<<(BATCH * NLOG) / 4, 256, 0, stream>>>(fbuf, wout, bout, out);
}

// Round 9
// 605.823 us; speedup vs baseline: 1.0974x; 1.0974x over previous
//
#include <hip/hip_runtime.h>
#include <hip/hip_bf16.h>

#define DIM 128
#define HIDDEN 384
#define BATCH 4
#define NDATA 100000
#define NEDGE 200000
#define NLOG 4096

typedef __bf16 bf16x8 __attribute__((ext_vector_type(8)));
typedef __bf16 bf16x2 __attribute__((ext_vector_type(2)));
typedef float f32x4 __attribute__((ext_vector_type(4)));
typedef unsigned short u16;
typedef unsigned int u32;

__device__ __forceinline__ u16 f2bf(float f) {
  __bf16 b = (__bf16)f;  // native RNE convert (v_cvt_pk_bf16_f32)
  return __builtin_bit_cast(u16, b);
}
// packed pair convert: single v_cvt_pk_bf16_f32
__device__ __forceinline__ u32 pk2bf(float lo, float hi) {
  bf16x2 t;
  t[0] = (__bf16)lo;
  t[1] = (__bf16)hi;
  return __builtin_bit_cast(u32, t);
}
__device__ __forceinline__ bf16x8 as_bf(uint4 u) {
  return __builtin_bit_cast(bf16x8, u);
}
// tanh via e^{2x}; v_rcp_f32 (1 ulp) -- abs err ~1e-7, << bf16 path error
__device__ __forceinline__ float fast_tanh(float x) {
  float xc = fminf(fmaxf(x, -15.f), 15.f);
  float t = __expf(2.f * xc);
  return (t - 1.f) * __builtin_amdgcn_rcpf(t + 1.f);
}

// ---------------------------------------------------------------------------
// CSR build: histogram -> scan -> scatter
// ---------------------------------------------------------------------------
__global__ void zero_counts_kernel(int* __restrict__ counts) {
  int i = blockIdx.x * blockDim.x + threadIdx.x;
  if (i < NLOG) counts[i] = 0;
}

__global__ void count_kernel(const int* __restrict__ dst, int* __restrict__ counts) {
  int e = blockIdx.x * blockDim.x + threadIdx.x;
  if (e < NEDGE) atomicAdd(&counts[dst[e]], 1);
}

__global__ __launch_bounds__(1024) void scan_kernel(const int* __restrict__ counts,
                                                    int* __restrict__ offsets,
                                                    int* __restrict__ cursor) {
  __shared__ int sdata[1024];
  const int t = threadIdx.x;
  const int c0 = counts[4 * t + 0];
  const int c1 = counts[4 * t + 1];
  const int c2 = counts[4 * t + 2];
  const int c3 = counts[4 * t + 3];
  const int s = c0 + c1 + c2 + c3;
  sdata[t] = s;
  __syncthreads();
  for (int off = 1; off < 1024; off <<= 1) {
    int vv = (t >= off) ? sdata[t - off] : 0;
    __syncthreads();
    sdata[t] += vv;
    __syncthreads();
  }
  const int excl = sdata[t] - s;
  const int o0 = excl, o1 = o0 + c0, o2 = o1 + c1, o3 = o2 + c2;
  offsets[4 * t + 0] = o0;
  offsets[4 * t + 1] = o1;
  offsets[4 * t + 2] = o2;
  offsets[4 * t + 3] = o3;
  cursor[4 * t + 0] = o0;
  cursor[4 * t + 1] = o1;
  cursor[4 * t + 2] = o2;
  cursor[4 * t + 3] = o3;
  if (t == 1023) offsets[NLOG] = o3 + c3;
}

__global__ void scatter_kernel(const int* __restrict__ src, const int* __restrict__ dst,
                               int* __restrict__ cursor, int* __restrict__ sorted_src) {
  int e = blockIdx.x * blockDim.x + threadIdx.x;
  if (e < NEDGE) {
    int d = dst[e];
    int pos = atomicAdd(&cursor[d], 1);
    sorted_src[pos] = src[e];
  }
}

// ---------------------------------------------------------------------------
// segment product over bf16 v_act [i][b][dim]: one block (ONE WAVE, 64 thr)
// per segment; each thread covers 8 bf16 = 16 B -> 64*16 = 1 KB = exactly
// one [b][dim] row per edge. R6-exact (R8's 4-wave split was neutral).
// ---------------------------------------------------------------------------
__device__ __forceinline__ void prod_accum(uint4 u, f32x4& plo, f32x4& phi) {
  f32x4 lo, hi;
  lo[0] = __uint_as_float(u.x << 16);
  lo[1] = __uint_as_float(u.x & 0xffff0000u);
  lo[2] = __uint_as_float(u.y << 16);
  lo[3] = __uint_as_float(u.y & 0xffff0000u);
  hi[0] = __uint_as_float(u.z << 16);
  hi[1] = __uint_as_float(u.z & 0xffff0000u);
  hi[2] = __uint_as_float(u.w << 16);
  hi[3] = __uint_as_float(u.w & 0xffff0000u);
  plo *= lo;
  phi *= hi;
}

__global__ __launch_bounds__(64) void prod_kernel_t(const u16* __restrict__ va,
                                                    const int* __restrict__ offsets,
                                                    const int* __restrict__ sorted_src,
                                                    float* __restrict__ l) {
  const int s = blockIdx.x;
  const int c = threadIdx.x;  // 0..63: covers bf16 elems 8c..8c+7 of the 512-elem row
  const int beg = offsets[s];
  const int end = offsets[s + 1];
  const u16* base = va + 8 * c;
  f32x4 plo[8], phi[8];
#pragma unroll
  for (int i = 0; i < 8; ++i) {
    plo[i] = {1.f, 1.f, 1.f, 1.f};
    phi[i] = {1.f, 1.f, 1.f, 1.f};
  }
  int e = beg;
  // scalar head until e is int4-aligned
  for (; e < end && (e & 3); ++e) {
    const uint4 u = *(const uint4*)(base + (size_t)sorted_src[e] * 512);
    prod_accum(u, plo[0], phi[0]);
  }
  for (; e + 8 <= end; e += 8) {
    const int4 ia = *(const int4*)(sorted_src + e);
    const int4 ib = *(const int4*)(sorted_src + e + 4);
    const int idx[8] = {ia.x, ia.y, ia.z, ia.w, ib.x, ib.y, ib.z, ib.w};
    uint4 r[8];
#pragma unroll
    for (int i = 0; i < 8; ++i) r[i] = *(const uint4*)(base + (size_t)idx[i] * 512);
#pragma unroll
    for (int i = 0; i < 8; ++i) prod_accum(r[i], plo[i], phi[i]);
  }
  for (; e < end; ++e) {
    const uint4 u = *(const uint4*)(base + (size_t)sorted_src[e] * 512);
    prod_accum(u, plo[0], phi[0]);
  }
  const f32x4 rlo =
      ((plo[0] * plo[1]) * (plo[2] * plo[3])) * ((plo[4] * plo[5]) * (plo[6] * plo[7]));
  const f32x4 rhi =
      ((phi[0] * phi[1]) * (phi[2] * phi[3])) * ((phi[4] * phi[5]) * (phi[6] * phi[7]));
  // elems 8c..8c+7 -> batch b = c>>4, dim d = (c&15)*8
  float* outp = l + ((size_t)(c >> 4) * NLOG + s) * DIM + (c & 15) * 8;
  *(f32x4*)outp = rlo;
  *(f32x4*)(outp + 4) = rhi;
}

// ---------------------------------------------------------------------------
// weight convert: fp32 -> bf16, transposed to [N][K] (K contiguous)
// ---------------------------------------------------------------------------
__global__ __launch_bounds__(256) void convert_w_kernel(
    const float* __restrict__ w1a, const float* __restrict__ w3a,
    const float* __restrict__ w2a, const float* __restrict__ w1b,
    const float* __restrict__ w3b, const float* __restrict__ w2b,
    u16* __restrict__ w1Ta, u16* __restrict__ w3Ta, u16* __restrict__ w2Ta,
    u16* __restrict__ w1Tb, u16* __restrict__ w3Tb, u16* __restrict__ w2Tb) {
  const int i = blockIdx.x * 256 + threadIdx.x;  // 0..49151 exact
  const int n1 = i >> 7, k1 = i & 127;           // w1T/w3T: [384][128]
  w1Ta[i] = f2bf(w1a[k1 * HIDDEN + n1]);
  w3Ta[i] = f2bf(w3a[k1 * HIDDEN + n1]);
  w1Tb[i] = f2bf(w1b[k1 * HIDDEN + n1]);
  w3Tb[i] = f2bf(w3b[k1 * HIDDEN + n1]);
  const int n2 = i / HIDDEN, k2 = i - n2 * HIDDEN;  // w2T: [128][384]
  w2Ta[i] = f2bf(w2a[k2 * DIM + n2]);
  w2Tb[i] = f2bf(w2b[k2 * DIM + n2]);
}

// ---------------------------------------------------------------------------
// Fused MFMA FFN, transposed GEMMs: D = W^T (A, global) x X^T (B, LDS).
// ROUND-9: 512 threads (8 waves) per 64-row tile, SAME 48 KB LDS, SAME
// per-wave amortization ratios (R2's trap avoided): each wave owns 48
// hidden (3 mt, GEMM1) and 16 output dims (1 mt, GEMM2). Per-wave work
// halves; resident waves 12 -> 16/CU (2 blocks x 8 waves) for latency
// hiding. No software prefetch (R4/R8: spills, 3x confirmed).
// LDS: xn[64][128]bf16 in [0,16K) until B-frags hoisted; gs[64][384] reuses.
// Swizzle: physical 16B chunk = logical ^ (row&7) on both write & read.
// mode: 1 = ffn1 (tanh + transposed BF16 store [i][b][dim]), 0 = ffn2 (f32).
// ---------------------------------------------------------------------------
__global__ __launch_bounds__(512, 2) void ffn_mfma_kernel(
    const float* __restrict__ xin, const float* __restrict__ rmsw,
    const u16* __restrict__ w1T, const u16* __restrict__ w3T,
    const u16* __restrict__ w2T, float* __restrict__ xout, int mode) {
  __shared__ alignas(16) u16 sm[24576];  // 49152 B
  char* const sb = (char*)sm;
  const int t = threadIdx.x;
  const int row0 = blockIdx.x * 64;

  // ---- Phase A: load + rmsnorm -> xn (bf16, swizzled 16B chunks) ----
  // 512 threads: r = t>>3 (0..63), q = t&7 (16-col slice); 8-lane reduce.
  {
    const int r = t >> 3;
    const int q = t & 7;
    const float* vr = xin + (size_t)(row0 + r) * DIM + q * 16;
    float av[16];
#pragma unroll
    for (int i = 0; i < 4; ++i) *(float4*)(av + 4 * i) = *(const float4*)(vr + 4 * i);
    float wr_[16];
#pragma unroll
    for (int i = 0; i < 4; ++i)
      *(float4*)(wr_ + 4 * i) = *(const float4*)(rmsw + q * 16 + 4 * i);
    float ss = 0.f;
#pragma unroll
    for (int i = 0; i < 16; ++i) ss += av[i] * av[i];
    ss += __shfl_xor(ss, 1);
    ss += __shfl_xor(ss, 2);
    ss += __shfl_xor(ss, 4);
    const float scale = __builtin_amdgcn_rsqf(ss * (1.0f / DIM) + 1e-5f);
    const int r7 = r & 7;
#pragma unroll
    for (int i = 0; i < 2; ++i) {
      uint4 pk;
      pk.x = pk2bf(av[8 * i + 0] * scale * wr_[8 * i + 0],
                   av[8 * i + 1] * scale * wr_[8 * i + 1]);
      pk.y = pk2bf(av[8 * i + 2] * scale * wr_[8 * i + 2],
                   av[8 * i + 3] * scale * wr_[8 * i + 3]);
      pk.z = pk2bf(av[8 * i + 4] * scale * wr_[8 * i + 4],
                   av[8 * i + 5] * scale * wr_[8 * i + 5]);
      pk.w = pk2bf(av[8 * i + 6] * scale * wr_[8 * i + 6],
                   av[8 * i + 7] * scale * wr_[8 * i + 7]);
      const int c = q * 2 + i;
      *(uint4*)(sb + r * 256 + ((c ^ r7) << 4)) = pk;
    }
  }
  __syncthreads();

  const int wv = t >> 6;  // 0..7
  const int lane = t & 63;
  const int m16 = lane & 15;
  const int quad = lane >> 4;
  const int m7 = m16 & 7;

  // ---- B-fragments (xn) hoisted once: all 64 rows x K=128 ----
  uint4 bfr[4][4];
#pragma unroll
  for (int nt = 0; nt < 4; ++nt) {
    const int row = nt * 16 + m16;
#pragma unroll
    for (int ks = 0; ks < 4; ++ks)
      bfr[nt][ks] = *(const uint4*)(sb + row * 256 + (((4 * ks + quad) ^ m7) << 4));
  }
  __syncthreads();  // xn region is now dead; gs may alias it

  // ---- GEMM1: H^T = {W1,W3}^T @ X^T; gs = silu(h1)*h3 -> LDS (b64) ----
  const int woff = wv * 48;  // this wave's hidden slice (48 rows, 3 mt)
#pragma unroll 1
  for (int mt = 0; mt < 3; ++mt) {
    const size_t wrow = (size_t)(woff + mt * 16 + m16) * DIM + quad * 8;
    uint4 a1[4], a3[4];
#pragma unroll
    for (int ks = 0; ks < 4; ++ks) {
      a1[ks] = *(const uint4*)(w1T + wrow + ks * 32);
      a3[ks] = *(const uint4*)(w3T + wrow + ks * 32);
    }
    f32x4 acc1[4] = {{0.f, 0.f, 0.f, 0.f}, {0.f, 0.f, 0.f, 0.f},
                     {0.f, 0.f, 0.f, 0.f}, {0.f, 0.f, 0.f, 0.f}};
    f32x4 acc3[4] = {{0.f, 0.f, 0.f, 0.f}, {0.f, 0.f, 0.f, 0.f},
                     {0.f, 0.f, 0.f, 0.f}, {0.f, 0.f, 0.f, 0.f}};
#pragma unroll
    for (int ks = 0; ks < 4; ++ks) {
      const bf16x8 fa1 = as_bf(a1[ks]);
      const bf16x8 fa3 = as_bf(a3[ks]);
#pragma unroll
      for (int nt = 0; nt < 4; ++nt) {
        const bf16x8 fb = as_bf(bfr[nt][ks]);
        acc1[nt] = __builtin_amdgcn_mfma_f32_16x16x32_bf16(fa1, fb, acc1[nt], 0, 0, 0);
        acc3[nt] = __builtin_amdgcn_mfma_f32_16x16x32_bf16(fa3, fb, acc3[nt], 0, 0, 0);
      }
    }
    // epilogue: lane holds 4 consecutive hidden (h0..h0+3) at 4 rows (nt)
    const int hch = (woff + mt * 16) >> 3;  // even chunk base (48wv+16mt)/8
    const int chu = (hch + (quad >> 1));
    const int half = (quad & 1) * 8;
#pragma unroll
    for (int nt = 0; nt < 4; ++nt) {
      const int row = nt * 16 + m16;
      float g[4];
#pragma unroll
      for (int r = 0; r < 4; ++r) {
        const float h1 = acc1[nt][r], h3 = acc3[nt][r];
        g[r] = h1 * __builtin_amdgcn_rcpf(1.0f + __expf(-h1)) * h3;
      }
      uint2 pk;
      pk.x = pk2bf(g[0], g[1]);
      pk.y = pk2bf(g[2], g[3]);
      *(uint2*)(sb + row * 768 + ((chu ^ m7) << 4) + half) = pk;
    }
  }
  __syncthreads();

  // ---- GEMM2: F^T = W2^T @ G^T (+residual); one 16-dim slice per wave ----
  {
    const size_t wrow = (size_t)(wv * 16 + m16) * HIDDEN + quad * 8;
    const int d0 = wv * 16 + quad * 4;
    uint4 aw[12];
#pragma unroll
    for (int ks = 0; ks < 12; ++ks) aw[ks] = *(const uint4*)(w2T + wrow + ks * 32);
#pragma unroll 1
    for (int nt = 0; nt < 4; ++nt) {
      const int row = nt * 16 + m16;
      uint4 bg[12];
#pragma unroll
      for (int ks = 0; ks < 12; ++ks)
        bg[ks] = *(const uint4*)(sb + row * 768 + (((4 * ks + quad) ^ m7) << 4));
      f32x4 acc = {0.f, 0.f, 0.f, 0.f};
#pragma unroll
      for (int ks = 0; ks < 12; ++ks)
        acc = __builtin_amdgcn_mfma_f32_16x16x32_bf16(as_bf(aw[ks]), as_bf(bg[ks]), acc,
                                                      0, 0, 0);
      const int grow = row0 + row;
      const float4 res = *(const float4*)(xin + (size_t)grow * DIM + d0);
      float4 o;
      o.x = acc[0] + res.x;
      o.y = acc[1] + res.y;
      o.z = acc[2] + res.z;
      o.w = acc[3] + res.w;
      if (mode) {  // ffn1: tanh + transposed BF16 store [i][b][dim]
        o.x = fast_tanh(o.x);
        o.y = fast_tanh(o.y);
        o.z = fast_tanh(o.z);
        o.w = fast_tanh(o.w);
        const int b = grow / NDATA;
        const int i = grow - b * NDATA;
        u16* const xb = (u16*)xout;
        uint2 pk;
        pk.x = pk2bf(o.x, o.y);
        pk.y = pk2bf(o.z, o.w);
        *(uint2*)(xb + ((size_t)i * BATCH + b) * DIM + d0) = pk;
      } else {
        *(float4*)(xout + (size_t)grow * DIM + d0) = o;
      }
    }
  }
}

// ---------------------------------------------------------------------------
// readout: out[row] = dot(fbuf[row], wout) + bout
// ---------------------------------------------------------------------------
__global__ __launch_bounds__(256) void readout_kernel(const float* __restrict__ fbuf,
                                                      const float* __restrict__ wout,
                                                      const float* __restrict__ bout,
                                                      float* __restrict__ out) {
  const int t = threadIdx.x;
  const int row = blockIdx.x * 4 + (t >> 6);
  const int lane = t & 63;
  const float2 f = *(const float2*)(fbuf + (size_t)row * DIM + lane * 2);
  const float2 w = *(const float2*)(wout + lane * 2);
  float s = f.x * w.x + f.y * w.y;
  s += __shfl_xor(s, 1);
  s += __shfl_xor(s, 2);
  s += __shfl_xor(s, 4);
  s += __shfl_xor(s, 8);
  s += __shfl_xor(s, 16);
  s += __shfl_xor(s, 32);
  if (lane == 0) out[row] = s + bout[0];
}

// ---------------------------------------------------------------------------
extern "C" void kernel_launch(void* const* d_in, const int* in_sizes, int n_in,
                              void* d_out, int out_size, void* d_ws, size_t ws_size,
                              hipStream_t stream) {
  const float* v = (const float*)d_in[0];
  const int* data_src = (const int*)d_in[1];
  const int* data_dst = (const int*)d_in[2];
  const float* rms1_w = (const float*)d_in[4];
  const float* w1a = (const float*)d_in[5];
  const float* w2a = (const float*)d_in[6];
  const float* w3a = (const float*)d_in[7];
  const float* rms2_w = (const float*)d_in[8];
  const float* w1b = (const float*)d_in[9];
  const float* w2b = (const float*)d_in[10];
  const float* w3b = (const float*)d_in[11];
  const float* wout = (const float*)d_in[12];
  const float* bout = (const float*)d_in[13];
  float* out = (float*)d_out;

  char* ws = (char*)d_ws;
  size_t off = 0;
  auto take = [&](size_t bytes) -> char* {
    char* p = ws + off;
    off += (bytes + 255) & ~(size_t)255;
    return p;
  };
  u16* v_act_t = (u16*)take((size_t)BATCH * NDATA * DIM * 2);  // [i][b][dim] bf16
  float* lbuf = (float*)take((size_t)BATCH * NLOG * DIM * 4);
  float* fbuf = (float*)take((size_t)BATCH * NLOG * DIM * 4);
  int* counts = (int*)take(NLOG * 4);
  int* offsets = (int*)take((NLOG + 1) * 4);
  int* cursor = (int*)take(NLOG * 4);
  int* sorted_src = (int*)take(NEDGE * 4);
  u16* w1Ta = (u16*)take(HIDDEN * DIM * 2);
  u16* w3Ta = (u16*)take(HIDDEN * DIM * 2);
  u16* w2Ta = (u16*)take(HIDDEN * DIM * 2);
  u16* w1Tb = (u16*)take(HIDDEN * DIM * 2);
  u16* w3Tb = (u16*)take(HIDDEN * DIM * 2);
  u16* w2Tb = (u16*)take(HIDDEN * DIM * 2);

  convert_w_kernel<<<(HIDDEN * DIM) / 256, 256, 0, stream>>>(
      w1a, w3a, w2a, w1b, w3b, w2b, w1Ta, w3Ta, w2Ta, w1Tb, w3Tb, w2Tb);
  zero_counts_kernel<<<(NLOG + 255) / 256, 256, 0, stream>>>(counts);
  count_kernel<<<(NEDGE + 255) / 256, 256, 0, stream>>>(data_dst, counts);
  scan_kernel<<<1, 1024, 0, stream>>>(counts, offsets, cursor);
  scatter_kernel<<<(NEDGE + 255) / 256, 256, 0, stream>>>(data_src, data_dst, cursor,
                                                          sorted_src);
  // FFN1 + tanh over 400k rows -> transposed bf16 v_act (8 waves/tile)
  ffn_mfma_kernel<<<(BATCH * NDATA) / 64, 512, 0, stream>>>(
      v, rms1_w, w1Ta, w3Ta, w2Ta, (float*)v_act_t, 1);
  // segment products over transposed bf16 layout (64 thr = exactly one row)
  prod_kernel_t<<<NLOG, 64, 0, stream>>>(v_act_t, offsets, sorted_src, lbuf);
  // FFN2 (flat f32) + readout
  ffn_mfma_kernel<<<(BATCH * NLOG) / 64, 512, 0, stream>>>(lbuf, rms2_w, w1Tb, w3Tb,
                                                           w2Tb, fbuf, 0);
  readout_kernel<<<(BATCH * NLOG) / 4, 256, 0, stream>>>(fbuf, wout, bout, out);
}

// Round 10
// 597.389 us; speedup vs baseline: 1.1129x; 1.0141x over previous
//
#include <hip/hip_runtime.h>
#include <hip/hip_bf16.h>

#define DIM 128
#define HIDDEN 384
#define BATCH 4
#define NDATA 100000
#define NEDGE 200000
#define NLOG 4096

typedef __bf16 bf16x8 __attribute__((ext_vector_type(8)));
typedef __bf16 bf16x2 __attribute__((ext_vector_type(2)));
typedef float f32x4 __attribute__((ext_vector_type(4)));
typedef unsigned short u16;
typedef unsigned int u32;

__device__ __forceinline__ u16 f2bf(float f) {
  __bf16 b = (__bf16)f;  // native RNE convert (v_cvt_pk_bf16_f32)
  return __builtin_bit_cast(u16, b);
}
// packed pair convert: single v_cvt_pk_bf16_f32
__device__ __forceinline__ u32 pk2bf(float lo, float hi) {
  bf16x2 t;
  t[0] = (__bf16)lo;
  t[1] = (__bf16)hi;
  return __builtin_bit_cast(u32, t);
}
__device__ __forceinline__ bf16x8 as_bf(uint4 u) {
  return __builtin_bit_cast(bf16x8, u);
}
// tanh via e^{2x}; v_rcp_f32 (1 ulp) -- abs err ~1e-7, << bf16 path error
__device__ __forceinline__ float fast_tanh(float x) {
  float xc = fminf(fmaxf(x, -15.f), 15.f);
  float t = __expf(2.f * xc);
  return (t - 1.f) * __builtin_amdgcn_rcpf(t + 1.f);
}

// ---------------------------------------------------------------------------
// CSR build: histogram -> scan -> scatter
// ---------------------------------------------------------------------------
__global__ void zero_counts_kernel(int* __restrict__ counts) {
  int i = blockIdx.x * blockDim.x + threadIdx.x;
  if (i < NLOG) counts[i] = 0;
}

__global__ void count_kernel(const int* __restrict__ dst, int* __restrict__ counts) {
  int e = blockIdx.x * blockDim.x + threadIdx.x;
  if (e < NEDGE) atomicAdd(&counts[dst[e]], 1);
}

__global__ __launch_bounds__(1024) void scan_kernel(const int* __restrict__ counts,
                                                    int* __restrict__ offsets,
                                                    int* __restrict__ cursor) {
  __shared__ int sdata[1024];
  const int t = threadIdx.x;
  const int c0 = counts[4 * t + 0];
  const int c1 = counts[4 * t + 1];
  const int c2 = counts[4 * t + 2];
  const int c3 = counts[4 * t + 3];
  const int s = c0 + c1 + c2 + c3;
  sdata[t] = s;
  __syncthreads();
  for (int off = 1; off < 1024; off <<= 1) {
    int vv = (t >= off) ? sdata[t - off] : 0;
    __syncthreads();
    sdata[t] += vv;
    __syncthreads();
  }
  const int excl = sdata[t] - s;
  const int o0 = excl, o1 = o0 + c0, o2 = o1 + c1, o3 = o2 + c2;
  offsets[4 * t + 0] = o0;
  offsets[4 * t + 1] = o1;
  offsets[4 * t + 2] = o2;
  offsets[4 * t + 3] = o3;
  cursor[4 * t + 0] = o0;
  cursor[4 * t + 1] = o1;
  cursor[4 * t + 2] = o2;
  cursor[4 * t + 3] = o3;
  if (t == 1023) offsets[NLOG] = o3 + c3;
}

__global__ void scatter_kernel(const int* __restrict__ src, const int* __restrict__ dst,
                               int* __restrict__ cursor, int* __restrict__ sorted_src) {
  int e = blockIdx.x * blockDim.x + threadIdx.x;
  if (e < NEDGE) {
    int d = dst[e];
    int pos = atomicAdd(&cursor[d], 1);
    sorted_src[pos] = src[e];
  }
}

// ---------------------------------------------------------------------------
// segment product over bf16 v_act [i][b][dim]: one block (ONE WAVE, 64 thr)
// per segment; each thread covers 8 bf16 = 16 B -> 64*16 = 1 KB = exactly
// one [b][dim] row per edge. R6-exact.
// ---------------------------------------------------------------------------
__device__ __forceinline__ void prod_accum(uint4 u, f32x4& plo, f32x4& phi) {
  f32x4 lo, hi;
  lo[0] = __uint_as_float(u.x << 16);
  lo[1] = __uint_as_float(u.x & 0xffff0000u);
  lo[2] = __uint_as_float(u.y << 16);
  lo[3] = __uint_as_float(u.y & 0xffff0000u);
  hi[0] = __uint_as_float(u.z << 16);
  hi[1] = __uint_as_float(u.z & 0xffff0000u);
  hi[2] = __uint_as_float(u.w << 16);
  hi[3] = __uint_as_float(u.w & 0xffff0000u);
  plo *= lo;
  phi *= hi;
}

__global__ __launch_bounds__(64) void prod_kernel_t(const u16* __restrict__ va,
                                                    const int* __restrict__ offsets,
                                                    const int* __restrict__ sorted_src,
                                                    float* __restrict__ l) {
  const int s = blockIdx.x;
  const int c = threadIdx.x;  // 0..63: covers bf16 elems 8c..8c+7 of the 512-elem row
  const int beg = offsets[s];
  const int end = offsets[s + 1];
  const u16* base = va + 8 * c;
  f32x4 plo[8], phi[8];
#pragma unroll
  for (int i = 0; i < 8; ++i) {
    plo[i] = {1.f, 1.f, 1.f, 1.f};
    phi[i] = {1.f, 1.f, 1.f, 1.f};
  }
  int e = beg;
  // scalar head until e is int4-aligned
  for (; e < end && (e & 3); ++e) {
    const uint4 u = *(const uint4*)(base + (size_t)sorted_src[e] * 512);
    prod_accum(u, plo[0], phi[0]);
  }
  for (; e + 8 <= end; e += 8) {
    const int4 ia = *(const int4*)(sorted_src + e);
    const int4 ib = *(const int4*)(sorted_src + e + 4);
    const int idx[8] = {ia.x, ia.y, ia.z, ia.w, ib.x, ib.y, ib.z, ib.w};
    uint4 r[8];
#pragma unroll
    for (int i = 0; i < 8; ++i) r[i] = *(const uint4*)(base + (size_t)idx[i] * 512);
#pragma unroll
    for (int i = 0; i < 8; ++i) prod_accum(r[i], plo[i], phi[i]);
  }
  for (; e < end; ++e) {
    const uint4 u = *(const uint4*)(base + (size_t)sorted_src[e] * 512);
    prod_accum(u, plo[0], phi[0]);
  }
  const f32x4 rlo =
      ((plo[0] * plo[1]) * (plo[2] * plo[3])) * ((plo[4] * plo[5]) * (plo[6] * plo[7]));
  const f32x4 rhi =
      ((phi[0] * phi[1]) * (phi[2] * phi[3])) * ((phi[4] * phi[5]) * (phi[6] * phi[7]));
  // elems 8c..8c+7 -> batch b = c>>4, dim d = (c&15)*8
  float* outp = l + ((size_t)(c >> 4) * NLOG + s) * DIM + (c & 15) * 8;
  *(f32x4*)outp = rlo;
  *(f32x4*)(outp + 4) = rhi;
}

// ---------------------------------------------------------------------------
// weight convert: fp32 -> bf16, transposed to [N][K] (K contiguous)
// ---------------------------------------------------------------------------
__global__ __launch_bounds__(256) void convert_w_kernel(
    const float* __restrict__ w1a, const float* __restrict__ w3a,
    const float* __restrict__ w2a, const float* __restrict__ w1b,
    const float* __restrict__ w3b, const float* __restrict__ w2b,
    u16* __restrict__ w1Ta, u16* __restrict__ w3Ta, u16* __restrict__ w2Ta,
    u16* __restrict__ w1Tb, u16* __restrict__ w3Tb, u16* __restrict__ w2Tb) {
  const int i = blockIdx.x * 256 + threadIdx.x;  // 0..49151 exact
  const int n1 = i >> 7, k1 = i & 127;           // w1T/w3T: [384][128]
  w1Ta[i] = f2bf(w1a[k1 * HIDDEN + n1]);
  w3Ta[i] = f2bf(w3a[k1 * HIDDEN + n1]);
  w1Tb[i] = f2bf(w1b[k1 * HIDDEN + n1]);
  w3Tb[i] = f2bf(w3b[k1 * HIDDEN + n1]);
  const int n2 = i / HIDDEN, k2 = i - n2 * HIDDEN;  // w2T: [128][384]
  w2Ta[i] = f2bf(w2a[k2 * DIM + n2]);
  w2Tb[i] = f2bf(w2b[k2 * DIM + n2]);
}

// ---------------------------------------------------------------------------
// FFN1 (R9-exact structure, mode-1 specialized): 512 threads (8 waves) per
// 64-row tile, 48 KB LDS, each wave owns 48 hidden (3 mt, GEMM1) and 16
// output dims (GEMM2). tanh + transposed BF16 store [i][b][dim].
// LDS: xn[64][128]bf16 in [0,16K) until B-frags hoisted; gs[64][384] reuses.
// Swizzle: physical 16B chunk = logical ^ (row&7) on both write & read.
// ---------------------------------------------------------------------------
__global__ __launch_bounds__(512, 2) void ffn1_kernel(
    const float* __restrict__ xin, const float* __restrict__ rmsw,
    const u16* __restrict__ w1T, const u16* __restrict__ w3T,
    const u16* __restrict__ w2T, u16* __restrict__ xout) {
  __shared__ alignas(16) u16 sm[24576];  // 49152 B
  char* const sb = (char*)sm;
  const int t = threadIdx.x;
  const int row0 = blockIdx.x * 64;

  // ---- Phase A: load + rmsnorm -> xn (bf16, swizzled 16B chunks) ----
  {
    const int r = t >> 3;
    const int q = t & 7;
    const float* vr = xin + (size_t)(row0 + r) * DIM + q * 16;
    float av[16];
#pragma unroll
    for (int i = 0; i < 4; ++i) *(float4*)(av + 4 * i) = *(const float4*)(vr + 4 * i);
    float wr_[16];
#pragma unroll
    for (int i = 0; i < 4; ++i)
      *(float4*)(wr_ + 4 * i) = *(const float4*)(rmsw + q * 16 + 4 * i);
    float ss = 0.f;
#pragma unroll
    for (int i = 0; i < 16; ++i) ss += av[i] * av[i];
    ss += __shfl_xor(ss, 1);
    ss += __shfl_xor(ss, 2);
    ss += __shfl_xor(ss, 4);
    const float scale = __builtin_amdgcn_rsqf(ss * (1.0f / DIM) + 1e-5f);
    const int r7 = r & 7;
#pragma unroll
    for (int i = 0; i < 2; ++i) {
      uint4 pk;
      pk.x = pk2bf(av[8 * i + 0] * scale * wr_[8 * i + 0],
                   av[8 * i + 1] * scale * wr_[8 * i + 1]);
      pk.y = pk2bf(av[8 * i + 2] * scale * wr_[8 * i + 2],
                   av[8 * i + 3] * scale * wr_[8 * i + 3]);
      pk.z = pk2bf(av[8 * i + 4] * scale * wr_[8 * i + 4],
                   av[8 * i + 5] * scale * wr_[8 * i + 5]);
      pk.w = pk2bf(av[8 * i + 6] * scale * wr_[8 * i + 6],
                   av[8 * i + 7] * scale * wr_[8 * i + 7]);
      const int c = q * 2 + i;
      *(uint4*)(sb + r * 256 + ((c ^ r7) << 4)) = pk;
    }
  }
  __syncthreads();

  const int wv = t >> 6;  // 0..7
  const int lane = t & 63;
  const int m16 = lane & 15;
  const int quad = lane >> 4;
  const int m7 = m16 & 7;

  // ---- B-fragments (xn) hoisted once: all 64 rows x K=128 ----
  uint4 bfr[4][4];
#pragma unroll
  for (int nt = 0; nt < 4; ++nt) {
    const int row = nt * 16 + m16;
#pragma unroll
    for (int ks = 0; ks < 4; ++ks)
      bfr[nt][ks] = *(const uint4*)(sb + row * 256 + (((4 * ks + quad) ^ m7) << 4));
  }
  __syncthreads();  // xn region is now dead; gs may alias it

  // ---- GEMM1: H^T = {W1,W3}^T @ X^T; gs = silu(h1)*h3 -> LDS (b64) ----
  const int woff = wv * 48;  // this wave's hidden slice (48 rows, 3 mt)
#pragma unroll 1
  for (int mt = 0; mt < 3; ++mt) {
    const size_t wrow = (size_t)(woff + mt * 16 + m16) * DIM + quad * 8;
    uint4 a1[4], a3[4];
#pragma unroll
    for (int ks = 0; ks < 4; ++ks) {
      a1[ks] = *(const uint4*)(w1T + wrow + ks * 32);
      a3[ks] = *(const uint4*)(w3T + wrow + ks * 32);
    }
    f32x4 acc1[4] = {{0.f, 0.f, 0.f, 0.f}, {0.f, 0.f, 0.f, 0.f},
                     {0.f, 0.f, 0.f, 0.f}, {0.f, 0.f, 0.f, 0.f}};
    f32x4 acc3[4] = {{0.f, 0.f, 0.f, 0.f}, {0.f, 0.f, 0.f, 0.f},
                     {0.f, 0.f, 0.f, 0.f}, {0.f, 0.f, 0.f, 0.f}};
#pragma unroll
    for (int ks = 0; ks < 4; ++ks) {
      const bf16x8 fa1 = as_bf(a1[ks]);
      const bf16x8 fa3 = as_bf(a3[ks]);
#pragma unroll
      for (int nt = 0; nt < 4; ++nt) {
        const bf16x8 fb = as_bf(bfr[nt][ks]);
        acc1[nt] = __builtin_amdgcn_mfma_f32_16x16x32_bf16(fa1, fb, acc1[nt], 0, 0, 0);
        acc3[nt] = __builtin_amdgcn_mfma_f32_16x16x32_bf16(fa3, fb, acc3[nt], 0, 0, 0);
      }
    }
    // epilogue: lane holds 4 consecutive hidden (h0..h0+3) at 4 rows (nt)
    const int hch = (woff + mt * 16) >> 3;  // even chunk base
    const int chu = (hch + (quad >> 1));
    const int half = (quad & 1) * 8;
#pragma unroll
    for (int nt = 0; nt < 4; ++nt) {
      const int row = nt * 16 + m16;
      float g[4];
#pragma unroll
      for (int r = 0; r < 4; ++r) {
        const float h1 = acc1[nt][r], h3 = acc3[nt][r];
        g[r] = h1 * __builtin_amdgcn_rcpf(1.0f + __expf(-h1)) * h3;
      }
      uint2 pk;
      pk.x = pk2bf(g[0], g[1]);
      pk.y = pk2bf(g[2], g[3]);
      *(uint2*)(sb + row * 768 + ((chu ^ m7) << 4) + half) = pk;
    }
  }
  __syncthreads();

  // ---- GEMM2: F^T = W2^T @ G^T (+residual); one 16-dim slice per wave ----
  {
    const size_t wrow = (size_t)(wv * 16 + m16) * HIDDEN + quad * 8;
    const int d0 = wv * 16 + quad * 4;
    uint4 aw[12];
#pragma unroll
    for (int ks = 0; ks < 12; ++ks) aw[ks] = *(const uint4*)(w2T + wrow + ks * 32);
#pragma unroll 1
    for (int nt = 0; nt < 4; ++nt) {
      const int row = nt * 16 + m16;
      uint4 bg[12];
#pragma unroll
      for (int ks = 0; ks < 12; ++ks)
        bg[ks] = *(const uint4*)(sb + row * 768 + (((4 * ks + quad) ^ m7) << 4));
      f32x4 acc = {0.f, 0.f, 0.f, 0.f};
#pragma unroll
      for (int ks = 0; ks < 12; ++ks)
        acc = __builtin_amdgcn_mfma_f32_16x16x32_bf16(as_bf(aw[ks]), as_bf(bg[ks]), acc,
                                                      0, 0, 0);
      const int grow = row0 + row;
      const float4 res = *(const float4*)(xin + (size_t)grow * DIM + d0);
      float o0 = fast_tanh(acc[0] + res.x);
      float o1 = fast_tanh(acc[1] + res.y);
      float o2 = fast_tanh(acc[2] + res.z);
      float o3 = fast_tanh(acc[3] + res.w);
      const int b = grow / NDATA;
      const int i = grow - b * NDATA;
      uint2 pk;
      pk.x = pk2bf(o0, o1);
      pk.y = pk2bf(o2, o3);
      *(uint2*)(xout + ((size_t)i * BATCH + b) * DIM + d0) = pk;
    }
  }
}

// ---------------------------------------------------------------------------
// FFN2 + fused readout (mode-0 specialized): same structure as FFN1 but
// output = dot(ffn2(x)+x, wout) + bout, reduced in-kernel:
// per-lane partial dot -> quad shfl-reduce -> 2 KB LDS cross-wave combine
// -> wave 0 writes out[row]. Eliminates fbuf + readout kernel.
// ---------------------------------------------------------------------------
__global__ __launch_bounds__(512, 2) void ffn2_kernel(
    const float* __restrict__ xin, const float* __restrict__ rmsw,
    const u16* __restrict__ w1T, const u16* __restrict__ w3T,
    const u16* __restrict__ w2T, const float* __restrict__ wout,
    const float* __restrict__ bout, float* __restrict__ out) {
  __shared__ alignas(16) u16 sm[24576];  // 49152 B
  char* const sb = (char*)sm;
  const int t = threadIdx.x;
  const int row0 = blockIdx.x * 64;

  // ---- Phase A: load + rmsnorm -> xn (bf16, swizzled 16B chunks) ----
  {
    const int r = t >> 3;
    const int q = t & 7;
    const float* vr = xin + (size_t)(row0 + r) * DIM + q * 16;
    float av[16];
#pragma unroll
    for (int i = 0; i < 4; ++i) *(float4*)(av + 4 * i) = *(const float4*)(vr + 4 * i);
    float wr_[16];
#pragma unroll
    for (int i = 0; i < 4; ++i)
      *(float4*)(wr_ + 4 * i) = *(const float4*)(rmsw + q * 16 + 4 * i);
    float ss = 0.f;
#pragma unroll
    for (int i = 0; i < 16; ++i) ss += av[i] * av[i];
    ss += __shfl_xor(ss, 1);
    ss += __shfl_xor(ss, 2);
    ss += __shfl_xor(ss, 4);
    const float scale = __builtin_amdgcn_rsqf(ss * (1.0f / DIM) + 1e-5f);
    const int r7 = r & 7;
#pragma unroll
    for (int i = 0; i < 2; ++i) {
      uint4 pk;
      pk.x = pk2bf(av[8 * i + 0] * scale * wr_[8 * i + 0],
                   av[8 * i + 1] * scale * wr_[8 * i + 1]);
      pk.y = pk2bf(av[8 * i + 2] * scale * wr_[8 * i + 2],
                   av[8 * i + 3] * scale * wr_[8 * i + 3]);
      pk.z = pk2bf(av[8 * i + 4] * scale * wr_[8 * i + 4],
                   av[8 * i + 5] * scale * wr_[8 * i + 5]);
      pk.w = pk2bf(av[8 * i + 6] * scale * wr_[8 * i + 6],
                   av[8 * i + 7] * scale * wr_[8 * i + 7]);
      const int c = q * 2 + i;
      *(uint4*)(sb + r * 256 + ((c ^ r7) << 4)) = pk;
    }
  }
  __syncthreads();

  const int wv = t >> 6;  // 0..7
  const int lane = t & 63;
  const int m16 = lane & 15;
  const int quad = lane >> 4;
  const int m7 = m16 & 7;

  // ---- B-fragments (xn) hoisted once ----
  uint4 bfr[4][4];
#pragma unroll
  for (int nt = 0; nt < 4; ++nt) {
    const int row = nt * 16 + m16;
#pragma unroll
    for (int ks = 0; ks < 4; ++ks)
      bfr[nt][ks] = *(const uint4*)(sb + row * 256 + (((4 * ks + quad) ^ m7) << 4));
  }
  __syncthreads();

  // ---- GEMM1 ----
  const int woff = wv * 48;
#pragma unroll 1
  for (int mt = 0; mt < 3; ++mt) {
    const size_t wrow = (size_t)(woff + mt * 16 + m16) * DIM + quad * 8;
    uint4 a1[4], a3[4];
#pragma unroll
    for (int ks = 0; ks < 4; ++ks) {
      a1[ks] = *(const uint4*)(w1T + wrow + ks * 32);
      a3[ks] = *(const uint4*)(w3T + wrow + ks * 32);
    }
    f32x4 acc1[4] = {{0.f, 0.f, 0.f, 0.f}, {0.f, 0.f, 0.f, 0.f},
                     {0.f, 0.f, 0.f, 0.f}, {0.f, 0.f, 0.f, 0.f}};
    f32x4 acc3[4] = {{0.f, 0.f, 0.f, 0.f}, {0.f, 0.f, 0.f, 0.f},
                     {0.f, 0.f, 0.f, 0.f}, {0.f, 0.f, 0.f, 0.f}};
#pragma unroll
    for (int ks = 0; ks < 4; ++ks) {
      const bf16x8 fa1 = as_bf(a1[ks]);
      const bf16x8 fa3 = as_bf(a3[ks]);
#pragma unroll
      for (int nt = 0; nt < 4; ++nt) {
        const bf16x8 fb = as_bf(bfr[nt][ks]);
        acc1[nt] = __builtin_amdgcn_mfma_f32_16x16x32_bf16(fa1, fb, acc1[nt], 0, 0, 0);
        acc3[nt] = __builtin_amdgcn_mfma_f32_16x16x32_bf16(fa3, fb, acc3[nt], 0, 0, 0);
      }
    }
    const int hch = (woff + mt * 16) >> 3;
    const int chu = (hch + (quad >> 1));
    const int half = (quad & 1) * 8;
#pragma unroll
    for (int nt = 0; nt < 4; ++nt) {
      const int row = nt * 16 + m16;
      float g[4];
#pragma unroll
      for (int r = 0; r < 4; ++r) {
        const float h1 = acc1[nt][r], h3 = acc3[nt][r];
        g[r] = h1 * __builtin_amdgcn_rcpf(1.0f + __expf(-h1)) * h3;
      }
      uint2 pk;
      pk.x = pk2bf(g[0], g[1]);
      pk.y = pk2bf(g[2], g[3]);
      *(uint2*)(sb + row * 768 + ((chu ^ m7) << 4) + half) = pk;
    }
  }
  __syncthreads();

  // ---- GEMM2 + fused readout ----
  float partial[4];
  {
    const size_t wrow = (size_t)(wv * 16 + m16) * HIDDEN + quad * 8;
    const int d0 = wv * 16 + quad * 4;
    uint4 aw[12];
#pragma unroll
    for (int ks = 0; ks < 12; ++ks) aw[ks] = *(const uint4*)(w2T + wrow + ks * 32);
    const float4 wo = *(const float4*)(wout + d0);
#pragma unroll 1
    for (int nt = 0; nt < 4; ++nt) {
      const int row = nt * 16 + m16;
      uint4 bg[12];
#pragma unroll
      for (int ks = 0; ks < 12; ++ks)
        bg[ks] = *(const uint4*)(sb + row * 768 + (((4 * ks + quad) ^ m7) << 4));
      f32x4 acc = {0.f, 0.f, 0.f, 0.f};
#pragma unroll
      for (int ks = 0; ks < 12; ++ks)
        acc = __builtin_amdgcn_mfma_f32_16x16x32_bf16(as_bf(aw[ks]), as_bf(bg[ks]), acc,
                                                      0, 0, 0);
      const int grow = row0 + row;
      const float4 res = *(const float4*)(xin + (size_t)grow * DIM + d0);
      partial[nt] = (acc[0] + res.x) * wo.x + (acc[1] + res.y) * wo.y +
                    (acc[2] + res.z) * wo.z + (acc[3] + res.w) * wo.w;
    }
  }
  // quad-reduce: lanes with same m16 across quad 0..3
#pragma unroll
  for (int nt = 0; nt < 4; ++nt) {
    partial[nt] += __shfl_xor(partial[nt], 16);
    partial[nt] += __shfl_xor(partial[nt], 32);
  }
  __syncthreads();  // all gs reads done; sb reusable
  float* const pl = (float*)sb;  // [8 wv][4 nt][16 m16] = 2 KB
  if (quad == 0) {
#pragma unroll
    for (int nt = 0; nt < 4; ++nt) pl[(wv * 4 + nt) * 16 + m16] = partial[nt];
  }
  __syncthreads();
  if (wv == 0) {
    const int nt = lane >> 4;
    const int m = lane & 15;
    float ssum = bout[0];
#pragma unroll
    for (int w = 0; w < 8; ++w) ssum += pl[(w * 4 + nt) * 16 + m];
    out[row0 + nt * 16 + m] = ssum;
  }
}

// ---------------------------------------------------------------------------
extern "C" void kernel_launch(void* const* d_in, const int* in_sizes, int n_in,
                              void* d_out, int out_size, void* d_ws, size_t ws_size,
                              hipStream_t stream) {
  const float* v = (const float*)d_in[0];
  const int* data_src = (const int*)d_in[1];
  const int* data_dst = (const int*)d_in[2];
  const float* rms1_w = (const float*)d_in[4];
  const float* w1a = (const float*)d_in[5];
  const float* w2a = (const float*)d_in[6];
  const float* w3a = (const float*)d_in[7];
  const float* rms2_w = (const float*)d_in[8];
  const float* w1b = (const float*)d_in[9];
  const float* w2b = (const float*)d_in[10];
  const float* w3b = (const float*)d_in[11];
  const float* wout = (const float*)d_in[12];
  const float* bout = (const float*)d_in[13];
  float* out = (float*)d_out;

  char* ws = (char*)d_ws;
  size_t off = 0;
  auto take = [&](size_t bytes) -> char* {
    char* p = ws + off;
    off += (bytes + 255) & ~(size_t)255;
    return p;
  };
  u16* v_act_t = (u16*)take((size_t)BATCH * NDATA * DIM * 2);  // [i][b][dim] bf16
  float* lbuf = (float*)take((size_t)BATCH * NLOG * DIM * 4);
  int* counts = (int*)take(NLOG * 4);
  int* offsets = (int*)take((NLOG + 1) * 4);
  int* cursor = (int*)take(NLOG * 4);
  int* sorted_src = (int*)take(NEDGE * 4);
  u16* w1Ta = (u16*)take(HIDDEN * DIM * 2);
  u16* w3Ta = (u16*)take(HIDDEN * DIM * 2);
  u16* w2Ta = (u16*)take(HIDDEN * DIM * 2);
  u16* w1Tb = (u16*)take(HIDDEN * DIM * 2);
  u16* w3Tb = (u16*)take(HIDDEN * DIM * 2);
  u16* w2Tb = (u16*)take(HIDDEN * DIM * 2);

  convert_w_kernel<<<(HIDDEN * DIM) / 256, 256, 0, stream>>>(
      w1a, w3a, w2a, w1b, w3b, w2b, w1Ta, w3Ta, w2Ta, w1Tb, w3Tb, w2Tb);
  zero_counts_kernel<<<(NLOG + 255) / 256, 256, 0, stream>>>(counts);
  count_kernel<<<(NEDGE + 255) / 256, 256, 0, stream>>>(data_dst, counts);
  scan_kernel<<<1, 1024, 0, stream>>>(counts, offsets, cursor);
  scatter_kernel<<<(NEDGE + 255) / 256, 256, 0, stream>>>(data_src, data_dst, cursor,
                                                          sorted_src);
  // FFN1 + tanh over 400k rows -> transposed bf16 v_act (8 waves/tile)
  ffn1_kernel<<<(BATCH * NDATA) / 64, 512, 0, stream>>>(v, rms1_w, w1Ta, w3Ta, w2Ta,
                                                        v_act_t);
  // segment products over transposed bf16 layout (64 thr = exactly one row)
  prod_kernel_t<<<NLOG, 64, 0, stream>>>(v_act_t, offsets, sorted_src, lbuf);
  // FFN2 + fused readout (fbuf and readout kernel eliminated)
  ffn2_kernel<<<(BATCH * NLOG) / 64, 512, 0, stream>>>(lbuf, rms2_w, w1Tb, w3Tb, w2Tb,
                                                       wout, bout, out);
}